// Round 11
// baseline (227.697 us; speedup 1.0000x reference)
//
#include <hip/hip_runtime.h>

#define T_STEPS 256
#define HID 40
#define EPB 16
#define NTHR 512           // 8 waves: 0-3 L0 tiles (3,3,2,2), 4-7 L1 tiles (3,3,2,2)
#define RR0 72             // L0 row stride (shorts): [h0(40) | x(16) | pad(16)]
#define RR1 56             // L1 row stride (shorts): [h1(40) | pad(16)]
#define P0 (16 * RR0)      // L0 parity stride = 1152 shorts
#define P1 (16 * RR1)      // L1 parity stride = 896 shorts
#define OL1 (2 * P0)       // L1 region offset = 2304 shorts
#define STOT (2 * P0 + 2 * P1)   // 4096 shorts = 8192 B

typedef __attribute__((ext_vector_type(8))) short bf16x8;
typedef __attribute__((ext_vector_type(4))) float f32x4;

__device__ __forceinline__ unsigned short bf16_rne(float v) {
    unsigned int x = __float_as_uint(v);
    unsigned int r = x + 0x7FFFu + ((x >> 16) & 1u);
    return (unsigned short)(r >> 16);
}
__device__ __forceinline__ unsigned short bf16_cvt(float v) {
    unsigned int r;
    asm("v_cvt_pk_bf16_f32 %0, %1, %2" : "=v"(r) : "v"(v), "v"(v));
    return (unsigned short)r;
}
// fast gates (r16-proven): v_exp_f32 = 2^x; v_rcp_f32 replaces IEEE divide
__device__ __forceinline__ float sigm(float v) {
    return __builtin_amdgcn_rcpf(1.0f + __builtin_amdgcn_exp2f(-1.4426950408889634f * v));
}
__device__ __forceinline__ float tanh_f(float v) {
    return 1.0f - 2.0f * __builtin_amdgcn_rcpf(__builtin_amdgcn_exp2f(2.8853900817779268f * v) + 1.0f);
}

#define MF(A_, B_, C_) C_ = __builtin_amdgcn_mfma_f32_16x16x32_bf16(A_, B_, C_, 0, 0, 0)
#define PINV(v) asm volatile("" : "+v"(v))

// r25: WAVE CONSOLIDATION on the r24 base. r24 (128us, 1195cy/step) exposed
// the LDS pipe as co-dominant: 42 duplicated ds_read_b128/step (10 L1 waves
// x 3 + 6 L0 x 2; every wave reads the SAME B operand) ~ 330-500cy + 196cy
// measured conflicts. 8 waves with 2-3 tiles each share every B-read across
// their tiles: 42 -> 20 reads/step. Total VALU unchanged (issue-bound sum);
// each SIMD gets one L0 + one L1 wave. R2 tried this and lost 9us because
// ~800cy of barrier-drain+splice overhead (since removed by r22/r24) masked
// the LDS saving. Everything else identical to r24: [h0|x] L0 row (chunk-1
// read delivers x, no splice), tid<256 x staging from 4-deep reg ring,
// single h0 write (L1 reads h0 from L0 region, per-parity addrs), lgkm-only
// raw barrier, 64x4+1 step loop.
#define BAR() asm volatile("s_waitcnt lgkmcnt(0)\n\ts_barrier" ::: "memory")

// A-frag over unified K-concat rows [h_self(40) | input(KX)] (r15-proven mapping).
__device__ bf16x8 afrag(const float* Whh, const float* Wih, int KX,
                        int rh, int rx, int c, int qrow) {
    bf16x8 f;
    #pragma unroll
    for (int j = 0; j < 8; ++j) f[j] = 0;
    #pragma unroll
    for (int j = 0; j < 8; ++j) {
        const int k = 32 * c + qrow * 8 + j;
        if (k < 40) {
            if (rh >= 0) f[j] = (short)bf16_rne(Whh[rh * 40 + k]);
        } else if (k < 40 + KX) {
            if (rx >= 0) f[j] = (short)bf16_rne(Wih[rx * KX + (k - 40)]);
        }
    }
    return f;
}

__global__ __launch_bounds__(NTHR, 4)
void gru2_kernel(const float* __restrict__ x,
                 const float* __restrict__ Wih0, const float* __restrict__ Whh0,
                 const float* __restrict__ bih0, const float* __restrict__ bhh0,
                 const float* __restrict__ Wih1, const float* __restrict__ Whh1,
                 const float* __restrict__ bih1, const float* __restrict__ bhh1,
                 float* __restrict__ out)
{
    __shared__ __align__(16) unsigned short S[STOT];

    const int tid  = threadIdx.x;
    const int wid  = tid >> 6;     // 0..7
    const int l    = tid & 63;
    const int col  = l & 15;       // example / MFMA col
    const int qrow = l >> 4;
    const int ps   = (l & 15) & 3; // slot (0=r,1=z,2=nx,3=nh)
    const int pu   = (l & 15) >> 2;
    const int e0   = blockIdx.x * EPB;

    const bool isL1 = wid >= 4;
    const int  m    = wid & 3;
    const int  NTIL = (m < 2) ? 3 : 2;
    const int  Tb   = (m < 2) ? 3 * m : 6 + 2 * (m - 2);

    const float* Whh = isL1 ? Whh1 : Whh0;
    const float* Wih = isL1 ? Wih1 : Wih0;
    const float* bih = isL1 ? bih1 : bih0;
    const float* bhh = isL1 ? bhh1 : bhh0;
    const int KX = isL1 ? 40 : 16;

    // ---- A-frags (up to 3 tiles x up to 3 chunks) + biases ----
    bf16x8 ZF;
    #pragma unroll
    for (int j = 0; j < 8; ++j) ZF[j] = 0;
    bf16x8 FA0=ZF,FA1=ZF,FA2=ZF, FB0=ZF,FB1=ZF,FB2=ZF, FC0=ZF,FC1=ZF,FC2=ZF;
    f32x4 BBA, BBB, BBC;
    {
#define RRX(u, RH, RX) \
        const int RH = (ps == 2) ? -1 : (ps == 0 ? (u) : ps == 1 ? 40 + (u) : 80 + (u)); \
        const int RX = (ps == 3) ? -1 : (ps == 0 ? (u) : ps == 1 ? 40 + (u) : 80 + (u));
        {
            const int u0 = 4 * (Tb + 0) + pu;
            RRX(u0, rh0, rx0);
            FA0 = afrag(Whh, Wih, KX, rh0, rx0, 0, qrow);
            FA1 = afrag(Whh, Wih, KX, rh0, rx0, 1, qrow);
            if (isL1) FA2 = afrag(Whh, Wih, KX, rh0, rx0, 2, qrow);
        }
        {
            const int u1 = 4 * (Tb + 1) + pu;
            RRX(u1, rh1, rx1);
            FB0 = afrag(Whh, Wih, KX, rh1, rx1, 0, qrow);
            FB1 = afrag(Whh, Wih, KX, rh1, rx1, 1, qrow);
            if (isL1) FB2 = afrag(Whh, Wih, KX, rh1, rx1, 2, qrow);
        }
        if (NTIL == 3) {
            const int u2 = 4 * (Tb + 2) + pu;
            RRX(u2, rh2, rx2);
            FC0 = afrag(Whh, Wih, KX, rh2, rx2, 0, qrow);
            FC1 = afrag(Whh, Wih, KX, rh2, rx2, 1, qrow);
            if (isL1) FC2 = afrag(Whh, Wih, KX, rh2, rx2, 2, qrow);
        }
        const int ucA = 4 * (Tb + 0) + qrow;
        const int ucB = 4 * (Tb + 1) + qrow;
        BBA[0] = bih[ucA] + bhh[ucA];
        BBA[1] = bih[40 + ucA] + bhh[40 + ucA];
        BBA[2] = bih[80 + ucA];
        BBA[3] = bhh[80 + ucA];
        BBB[0] = bih[ucB] + bhh[ucB];
        BBB[1] = bih[40 + ucB] + bhh[40 + ucB];
        BBB[2] = bih[80 + ucB];
        BBB[3] = bhh[80 + ucB];
        if (NTIL == 3) {
            const int ucC = 4 * (Tb + 2) + qrow;
            BBC[0] = bih[ucC] + bhh[ucC];
            BBC[1] = bih[40 + ucC] + bhh[40 + ucC];
            BBC[2] = bih[80 + ucC];
            BBC[3] = bhh[80 + ucC];
        } else {
            BBC[0] = BBC[1] = BBC[2] = BBC[3] = 0.f;
        }
    }
    PINV(FA0); PINV(FA1); PINV(FA2);
    PINV(FB0); PINV(FB1); PINV(FB2);
    PINV(FC0); PINV(FC1); PINV(FC2);
    PINV(BBA); PINV(BBB); PINV(BBC);

    // ---- per-lane LDS addresses (shorts; parity compile-time at use) ----
    // L0 row [h0(40)|x(16)|pad(16)]: chunk0 at 8q..; chunk1 at 32+8q..:
    // qrow0 h0[32..39], qrow1 x[0..7], qrow2 x[8..15], qrow3 pad=0.
    const int rd0 = col * RR0 + 8 * qrow;
    const int rd1 = rd0 + 32;
    // L1 concat [h1(40) | h0(40)]: group g = 4c + qrow; h1 stride P1, h0
    // stride P0 -> precompute both parities.
    int g0p0, g0p1, g1p0, g1p1, g2p0, g2p1;
    {
        auto ga = [&](int g, int p) -> int {
            if (g < 5)  return OL1 + p * P1 + col * RR1 + 8 * g;      // h1
            if (g < 10) return p * P0 + col * RR0 + 8 * (g - 5);      // h0
            return p * P0 + col * RR0;                                // dead (A=0)
        };
        g0p0 = ga(qrow, 0);     g0p1 = ga(qrow, 1);
        g1p0 = ga(4 + qrow, 0); g1p1 = ga(4 + qrow, 1);
        g2p0 = ga(8 + qrow, 0); g2p1 = ga(8 + qrow, 1);
    }
    // write offsets per tile (parity (1-RP) applied as immediate)
    const int wbase = isL1 ? (OL1 + col * RR1) : (col * RR0);
    const int wA = wbase + 4 * (Tb + 0) + qrow;
    const int wB = wbase + 4 * (Tb + 1) + qrow;
    const int wC = wbase + 4 * (Tb + 2) + qrow;
    const int wP = isL1 ? P1 : P0;
    unsigned short* Sb = &S[0];
    float hA = 0.f, hB = 0.f, hC = 0.f;

    // ---- x staging lanes: tid<256 (= waves 0-3, all L0), one scalar each ----
    const bool xth = tid < 256;
    const int xe = tid >> 4, xk = tid & 15;
    const int xsl = xe * RR0 + 40 + xk;                // + parity at use
    const float* xrow = x + (size_t)(e0 + xe) * (T_STEPS * 16) + xk;

    // ---- zero LDS (initial h = 0; pads must stay 0) ----
    for (int idx = tid; idx < STOT; idx += NTHR) Sb[idx] = 0;
    __syncthreads();
    // x[0] into parity 0; ring holds x[1..4]
    float XA = 0.f, XB = 0.f, XC = 0.f, XD = 0.f;
    if (xth) {
        Sb[xsl] = bf16_cvt(xrow[0]);
        XA = xrow[16];       // x[1]
        XB = xrow[32];       // x[2]
        XC = xrow[48];       // x[3]
        XD = xrow[64];       // x[4]
    }
    __syncthreads();

#define GMATH(C, H) \
    const float r_ = sigm(C[0]); \
    const float z_ = sigm(C[1]); \
    const float n_ = tanh_f(C[2] + r_ * C[3]); \
    H = n_ + z_ * (H - n_);

    // BODY(RP, XQ): step t. XQ holds x[t+1]; write to parity (1-RP), refill
    // with x[t+5].
#define BODY(RP, XQ) { \
    if (!isL1) { \
        if (xth && t < T_STEPS - 1) { \
            Sb[xsl + (1 - (RP)) * P0] = bf16_cvt(XQ); \
            if (t + 5 < T_STEPS) XQ = xrow[(t + 5) * 16]; \
        } \
        if (t < T_STEPS) { \
            const bf16x8 S0 = *(const bf16x8*)(Sb + rd0 + (RP) * P0); \
            const bf16x8 S1 = *(const bf16x8*)(Sb + rd1 + (RP) * P0); \
            f32x4 c0 = __builtin_amdgcn_mfma_f32_16x16x32_bf16(FA0, S0, BBA, 0, 0, 0); \
            MF(FA1, S1, c0); \
            { GMATH(c0, hA); Sb[wA + (1 - (RP)) * P0] = bf16_cvt(hA); } \
            f32x4 c1 = __builtin_amdgcn_mfma_f32_16x16x32_bf16(FB0, S0, BBB, 0, 0, 0); \
            MF(FB1, S1, c1); \
            { GMATH(c1, hB); Sb[wB + (1 - (RP)) * P0] = bf16_cvt(hB); } \
            if (NTIL == 3) { \
                f32x4 c2 = __builtin_amdgcn_mfma_f32_16x16x32_bf16(FC0, S0, BBC, 0, 0, 0); \
                MF(FC1, S1, c2); \
                GMATH(c2, hC); Sb[wC + (1 - (RP)) * P0] = bf16_cvt(hC); \
            } \
        } \
    } else { \
        const bf16x8 S0 = *(const bf16x8*)(Sb + ((RP) ? g0p1 : g0p0)); \
        const bf16x8 S1 = *(const bf16x8*)(Sb + ((RP) ? g1p1 : g1p0)); \
        const bf16x8 S2 = *(const bf16x8*)(Sb + ((RP) ? g2p1 : g2p0)); \
        f32x4 c0 = __builtin_amdgcn_mfma_f32_16x16x32_bf16(FA0, S0, BBA, 0, 0, 0); \
        MF(FA1, S1, c0); MF(FA2, S2, c0); \
        f32x4 c1 = __builtin_amdgcn_mfma_f32_16x16x32_bf16(FB0, S0, BBB, 0, 0, 0); \
        MF(FB1, S1, c1); MF(FB2, S2, c1); \
        if (t > 0) { \
            { GMATH(c0, hA); Sb[wA + (1 - (RP)) * P1] = bf16_cvt(hA); } \
            { GMATH(c1, hB); Sb[wB + (1 - (RP)) * P1] = bf16_cvt(hB); } \
        } \
        if (NTIL == 3) { \
            f32x4 c2 = __builtin_amdgcn_mfma_f32_16x16x32_bf16(FC0, S0, BBC, 0, 0, 0); \
            MF(FC1, S1, c2); MF(FC2, S2, c2); \
            if (t > 0) { GMATH(c2, hC); Sb[wC + (1 - (RP)) * P1] = bf16_cvt(hC); } \
        } \
    } \
    ++t; \
    BAR(); }

    int t = 0;
    #pragma unroll 1
    for (int it = 0; it < 64; ++it) {
        BODY(0, XA)
        BODY(1, XB)
        BODY(0, XC)
        BODY(1, XD)
    }
    BODY(0, XA)   // t = 256: L1 finishes h1[255]; L0 inactive

    // ---- h1[255] straight from registers (4 L1 waves x 2-3 tiles x 4 units) ----
    if (isL1) {
        float* op = out + (size_t)(e0 + col) * HID + 4 * Tb + qrow;
        op[0] = hA;
        op[4] = hB;
        if (NTIL == 3) op[8] = hC;
    }
}

extern "C" void kernel_launch(void* const* d_in, const int* in_sizes, int n_in,
                              void* d_out, int out_size, void* d_ws, size_t ws_size,
                              hipStream_t stream) {
    const float* x    = (const float*)d_in[0];
    const float* Wih0 = (const float*)d_in[1];
    const float* Whh0 = (const float*)d_in[2];
    const float* bih0 = (const float*)d_in[3];
    const float* bhh0 = (const float*)d_in[4];
    const float* Wih1 = (const float*)d_in[5];
    const float* Whh1 = (const float*)d_in[6];
    const float* bih1 = (const float*)d_in[7];
    const float* bhh1 = (const float*)d_in[8];
    float* out = (float*)d_out;

    dim3 grid(4096 / EPB), block(NTHR);
    hipLaunchKernelGGL(gru2_kernel, grid, block, 0, stream,
                       x, Wih0, Whh0, bih0, bhh0, Wih1, Whh1, bih1, bhh1, out);
}

// Round 12
// 207.933 us; speedup vs baseline: 1.0951x; 1.0951x over previous
//
#include <hip/hip_runtime.h>

#define T_STEPS 256
#define HID 40
#define EPB 16
#define NTHR 1024          // 16 waves: 0-5 L0 (tiles 2,2,2,2,1,1), 6-15 L1 (1 tile)
#define RR0 72             // L0 row stride (shorts): [h0(40) | x(16) | pad(16)] = 36 dw
#define RR1 72             // L1 row stride (shorts): [h1(40) | pad(32)] = 36 dw (r26: was 56)
#define P0 (16 * RR0)      // L0 parity stride = 1152 shorts (576 dw = 18*32: bank-neutral)
#define P1 (16 * RR1)      // L1 parity stride = 1152 shorts (bank-neutral)
#define OL1 (2 * P0)       // L1 region offset = 2304 shorts (1152 dw = 36*32: bank-neutral)
#define STOT (2 * P0 + 2 * P1)   // 4608 shorts = 9216 B

typedef __attribute__((ext_vector_type(8))) short bf16x8;
typedef __attribute__((ext_vector_type(4))) float f32x4;

__device__ __forceinline__ unsigned short bf16_rne(float v) {
    unsigned int x = __float_as_uint(v);
    unsigned int r = x + 0x7FFFu + ((x >> 16) & 1u);
    return (unsigned short)(r >> 16);
}
__device__ __forceinline__ unsigned short bf16_cvt(float v) {
    unsigned int r;
    asm("v_cvt_pk_bf16_f32 %0, %1, %2" : "=v"(r) : "v"(v), "v"(v));
    return (unsigned short)r;
}
// fast gates (r16-proven): v_exp_f32 = 2^x; v_rcp_f32 replaces IEEE divide
__device__ __forceinline__ float sigm(float v) {
    return __builtin_amdgcn_rcpf(1.0f + __builtin_amdgcn_exp2f(-1.4426950408889634f * v));
}
__device__ __forceinline__ float tanh_f(float v) {
    return 1.0f - 2.0f * __builtin_amdgcn_rcpf(__builtin_amdgcn_exp2f(2.8853900817779268f * v) + 1.0f);
}

#define MF(A_, B_, C_) C_ = __builtin_amdgcn_mfma_f32_16x16x32_bf16(A_, B_, C_, 0, 0, 0)
#define PINV(v) asm volatile("" : "+v"(v))

// r26 = r24 (128us, best) + BANK-UNIFORM L1 ROWS. Analysis: wave64
// ds_read_b128 is inherently 8 LDS phases; excess conflict only from
// non-uniform bank spread. L0 reads (stride 36 dw): bank = 4(col+qrow)+d
// mod 32 -> exactly uniform, conflict-free. L1's concat reads MIXED strides
// in one instruction (h1 rows 28 dw, h0 rows 36 dw) -> 3-4-way collisions =
// the measured 1.29e7 conflicts (~196cy/step/CU, 16% of the 1195cy step).
// Fix: RR1=72 so BOTH regions stride 36 dw; P1/OL1 stay == 0 mod 32 dw ->
// every b128 read bank-uniform. One-constant change on the proven kernel.
//
// r25 (8 waves) confirmed read-DUPLICATION is not binding: halved reads,
// -39% conflicts, +22us. TLP (4 waves/SIMD) is what sets the pace.
#define BAR() asm volatile("s_waitcnt lgkmcnt(0)\n\ts_barrier" ::: "memory")

// A-frag over unified K-concat rows [h_self(40) | input(KX)] (r15-proven mapping).
__device__ bf16x8 afrag(const float* Whh, const float* Wih, int KX,
                        int rh, int rx, int c, int qrow) {
    bf16x8 f;
    #pragma unroll
    for (int j = 0; j < 8; ++j) f[j] = 0;
    #pragma unroll
    for (int j = 0; j < 8; ++j) {
        const int k = 32 * c + qrow * 8 + j;
        if (k < 40) {
            if (rh >= 0) f[j] = (short)bf16_rne(Whh[rh * 40 + k]);
        } else if (k < 40 + KX) {
            if (rx >= 0) f[j] = (short)bf16_rne(Wih[rx * KX + (k - 40)]);
        }
    }
    return f;
}

__global__ __launch_bounds__(NTHR, 4)
void gru2_kernel(const float* __restrict__ x,
                 const float* __restrict__ Wih0, const float* __restrict__ Whh0,
                 const float* __restrict__ bih0, const float* __restrict__ bhh0,
                 const float* __restrict__ Wih1, const float* __restrict__ Whh1,
                 const float* __restrict__ bih1, const float* __restrict__ bhh1,
                 float* __restrict__ out)
{
    __shared__ __align__(16) unsigned short S[STOT];

    const int tid  = threadIdx.x;
    const int wid  = tid >> 6;     // 0..15
    const int l    = tid & 63;
    const int col  = l & 15;       // example / MFMA col
    const int qrow = l >> 4;
    const int ps   = (l & 15) & 3; // slot (0=r,1=z,2=nx,3=nh)
    const int pu   = (l & 15) >> 2;
    const int e0   = blockIdx.x * EPB;

    const bool isL1 = wid >= 6;
    const int  NT   = (!isL1 && wid < 4) ? 2 : 1;
    const int  TA   = isL1 ? (wid - 6) : (wid < 4 ? 2 * wid : wid + 4);
    const int  TB   = (NT == 2) ? TA + 1 : TA;
    const bool dB   = (NT != 2);

    const float* Whh = isL1 ? Whh1 : Whh0;
    const float* Wih = isL1 ? Wih1 : Wih0;
    const float* bih = isL1 ? bih1 : bih0;
    const float* bhh = isL1 ? bhh1 : bhh0;
    const int KX = isL1 ? 40 : 16;

    // ---- A-frags + biases ----
    bf16x8 ZF;
    #pragma unroll
    for (int j = 0; j < 8; ++j) ZF[j] = 0;
    bf16x8 F00=ZF,F01=ZF,F02=ZF, F10=ZF,F11=ZF;
    f32x4 BB0, BB1;
    {
#define RRX(u, RH, RX) \
        const int RH = (ps == 2) ? -1 : (ps == 0 ? (u) : ps == 1 ? 40 + (u) : 80 + (u)); \
        const int RX = (ps == 3) ? -1 : (ps == 0 ? (u) : ps == 1 ? 40 + (u) : 80 + (u));
        {
            const int u0 = 4 * TA + pu;
            RRX(u0, rh0, rx0);
            F00 = afrag(Whh, Wih, KX, rh0, rx0, 0, qrow);
            F01 = afrag(Whh, Wih, KX, rh0, rx0, 1, qrow);
            if (isL1) F02 = afrag(Whh, Wih, KX, rh0, rx0, 2, qrow);
        }
        if (NT == 2) {
            const int u1 = 4 * TB + pu;
            RRX(u1, rh1, rx1);
            F10 = afrag(Whh, Wih, KX, rh1, rx1, 0, qrow);
            F11 = afrag(Whh, Wih, KX, rh1, rx1, 1, qrow);
        }
        const int uc0 = 4 * TA + qrow;
        const int uc1 = 4 * TB + qrow;
        BB0[0] = bih[uc0] + bhh[uc0];
        BB0[1] = bih[40 + uc0] + bhh[40 + uc0];
        BB0[2] = bih[80 + uc0];
        BB0[3] = bhh[80 + uc0];
        BB1[0] = dB ? 0.f : (bih[uc1] + bhh[uc1]);
        BB1[1] = dB ? 0.f : (bih[40 + uc1] + bhh[40 + uc1]);
        BB1[2] = dB ? 0.f : bih[80 + uc1];
        BB1[3] = dB ? 0.f : bhh[80 + uc1];
    }
    PINV(F00); PINV(F01); PINV(F02);
    PINV(F10); PINV(F11);
    PINV(BB0); PINV(BB1);

    // ---- per-lane LDS addresses (shorts; parity selected at compile time) ----
    // L0 row [h0(40)|x(16)|pad(16)]: chunk0 at 8q..; chunk1 at 32+8q..:
    // qrow0 h0[32..39], qrow1 x[0..7], qrow2 x[8..15], qrow3 pad=0.
    const int rd0 = col * RR0 + 8 * qrow;
    const int rd1 = rd0 + 32;
    // L1 concat [h1(40) | h0(40)]: group g = 4c + qrow; both regions now
    // stride 36 dw -> bank-uniform; precompute both parities.
    int g0p0, g0p1, g1p0, g1p1, g2p0, g2p1;
    {
        auto ga = [&](int g, int p) -> int {
            if (g < 5)  return OL1 + p * P1 + col * RR1 + 8 * g;      // h1
            if (g < 10) return p * P0 + col * RR0 + 8 * (g - 5);      // h0
            return p * P0 + col * RR0;                                // dead (A=0)
        };
        g0p0 = ga(qrow, 0);     g0p1 = ga(qrow, 1);
        g1p0 = ga(4 + qrow, 0); g1p1 = ga(4 + qrow, 1);
        g2p0 = ga(8 + qrow, 0); g2p1 = ga(8 + qrow, 1);
    }
    // write offsets (parity (1-RP) applied as compile-time immediate)
    const int w0  = col * RR0 + 4 * TA + qrow;         // L0 tile A unit
    const int w0b = col * RR0 + 4 * TB + qrow;         // L0 tile B unit
    const int w1  = OL1 + col * RR1 + 4 * TA + qrow;   // L1 unit
    unsigned short* Sb = &S[0];
    float hA0 = 0.f, hA1 = 0.f;

    // ---- x staging lanes: tid<256, one (example, feature) scalar each ----
    const bool xth = tid < 256;
    const int xe = tid >> 4, xk = tid & 15;
    const int xsl = xe * RR0 + 40 + xk;                // + parity at use
    const float* xrow = x + (size_t)(e0 + xe) * (T_STEPS * 16) + xk;

    // ---- zero LDS (initial h = 0; pads must stay 0) ----
    for (int idx = tid; idx < STOT; idx += NTHR) Sb[idx] = 0;
    __syncthreads();
    // x[0] into parity 0; ring holds x[1..4]
    float XA = 0.f, XB = 0.f, XC = 0.f, XD = 0.f;
    if (xth) {
        Sb[xsl] = bf16_cvt(xrow[0]);
        XA = xrow[16];       // x[1]
        XB = xrow[32];       // x[2]
        XC = xrow[48];       // x[3]
        XD = xrow[64];       // x[4]
    }
    __syncthreads();

#define GMATH(C, H) \
    const float r_ = sigm(C[0]); \
    const float z_ = sigm(C[1]); \
    const float n_ = tanh_f(C[2] + r_ * C[3]); \
    H = n_ + z_ * (H - n_);

    // BODY(RP, XQ): step t. XQ holds x[t+1]; write it to parity (1-RP) for
    // step t+1, then refill XQ with x[t+5] (used again at step t+4).
#define BODY(RP, XQ) { \
    if (!isL1) { \
        if (xth && t < T_STEPS - 1) { \
            Sb[xsl + (1 - (RP)) * P0] = bf16_cvt(XQ); \
            if (t + 5 < T_STEPS) XQ = xrow[(t + 5) * 16]; \
        } \
        if (t < T_STEPS) { \
            const bf16x8 S0 = *(const bf16x8*)(Sb + rd0 + (RP) * P0); \
            const bf16x8 S1 = *(const bf16x8*)(Sb + rd1 + (RP) * P0); \
            f32x4 c0 = __builtin_amdgcn_mfma_f32_16x16x32_bf16(F00, S0, BB0, 0, 0, 0); \
            MF(F01, S1, c0); \
            { GMATH(c0, hA0); Sb[w0 + (1 - (RP)) * P0] = bf16_cvt(hA0); } \
            if (NT == 2) { \
                f32x4 c1 = __builtin_amdgcn_mfma_f32_16x16x32_bf16(F10, S0, BB1, 0, 0, 0); \
                MF(F11, S1, c1); \
                GMATH(c1, hA1); Sb[w0b + (1 - (RP)) * P0] = bf16_cvt(hA1); \
            } \
        } \
    } else { \
        const bf16x8 S0 = *(const bf16x8*)(Sb + ((RP) ? g0p1 : g0p0)); \
        const bf16x8 S1 = *(const bf16x8*)(Sb + ((RP) ? g1p1 : g1p0)); \
        const bf16x8 S2 = *(const bf16x8*)(Sb + ((RP) ? g2p1 : g2p0)); \
        f32x4 c = __builtin_amdgcn_mfma_f32_16x16x32_bf16(F00, S0, BB0, 0, 0, 0); \
        MF(F01, S1, c); MF(F02, S2, c); \
        if (t > 0) { GMATH(c, hA0); Sb[w1 + (1 - (RP)) * P1] = bf16_cvt(hA0); } \
    } \
    ++t; \
    BAR(); }

    int t = 0;
    #pragma unroll 1
    for (int it = 0; it < 64; ++it) {
        BODY(0, XA)
        BODY(1, XB)
        BODY(0, XC)
        BODY(1, XD)
    }
    BODY(0, XA)   // t = 256: L1 finishes h1[255]; L0 inactive

    // ---- h1[255] straight from registers (10 L1 waves x 4 units = 40) ----
    if (isL1) {
        out[(size_t)(e0 + col) * HID + 4 * TA + qrow] = hA0;
    }
}

extern "C" void kernel_launch(void* const* d_in, const int* in_sizes, int n_in,
                              void* d_out, int out_size, void* d_ws, size_t ws_size,
                              hipStream_t stream) {
    const float* x    = (const float*)d_in[0];
    const float* Wih0 = (const float*)d_in[1];
    const float* Whh0 = (const float*)d_in[2];
    const float* bih0 = (const float*)d_in[3];
    const float* bhh0 = (const float*)d_in[4];
    const float* Wih1 = (const float*)d_in[5];
    const float* Whh1 = (const float*)d_in[6];
    const float* bih1 = (const float*)d_in[7];
    const float* bhh1 = (const float*)d_in[8];
    float* out = (float*)d_out;

    dim3 grid(4096 / EPB), block(NTHR);
    hipLaunchKernelGGL(gru2_kernel, grid, block, 0, stream,
                       x, Wih0, Whh0, bih0, bhh0, Wih1, Whh1, bih1, bhh1, out);
}

// Round 13
// 207.210 us; speedup vs baseline: 1.0989x; 1.0035x over previous
//
#include <hip/hip_runtime.h>

#define T_STEPS 256
#define HID 40
#define EPB 16
#define NTHR 1024          // 16 waves: 0-5 L0 (tiles 2,2,2,2,1,1), 6-15 L1 (1 tile)
#define RR0 72             // L0 row stride (shorts): [h0(40) | x(16) | pad(16)] = 36 dw
#define RR1 72             // L1 row stride (shorts): [h1(40) | pad(32)] = 36 dw
#define P0 (16 * RR0)      // L0 parity stride = 1152 shorts
#define P1 (16 * RR1)      // L1 parity stride = 1152 shorts
#define OL1 (2 * P0)       // L1 region offset = 2304 shorts
#define STOT (2 * P0 + 2 * P1)   // 4608 shorts = 9216 B

typedef __attribute__((ext_vector_type(8))) short bf16x8;
typedef __attribute__((ext_vector_type(4))) float f32x4;

__device__ __forceinline__ unsigned short bf16_rne(float v) {
    unsigned int x = __float_as_uint(v);
    unsigned int r = x + 0x7FFFu + ((x >> 16) & 1u);
    return (unsigned short)(r >> 16);
}
__device__ __forceinline__ unsigned short bf16_cvt(float v) {
    unsigned int r;
    asm("v_cvt_pk_bf16_f32 %0, %1, %2" : "=v"(r) : "v"(v), "v"(v));
    return (unsigned short)r;
}
// fast gates (r16-proven): v_exp_f32 = 2^x; v_rcp_f32 replaces IEEE divide
__device__ __forceinline__ float sigm(float v) {
    return __builtin_amdgcn_rcpf(1.0f + __builtin_amdgcn_exp2f(-1.4426950408889634f * v));
}
__device__ __forceinline__ float tanh_f(float v) {
    return 1.0f - 2.0f * __builtin_amdgcn_rcpf(__builtin_amdgcn_exp2f(2.8853900817779268f * v) + 1.0f);
}

#define MF(A_, B_, C_) C_ = __builtin_amdgcn_mfma_f32_16x16x32_bf16(A_, B_, C_, 0, 0, 0)
#define PINV(v) asm volatile("" : "+v"(v))

// r27 = r26 + X-DUTY REBALANCE. Evidence r24 vs r26: bank-uniform reads left
// conflicts AND time identical -> conflicts are in scattered b16 writes, off
// the critical path. Remaining model: step time = slowest wave in the
// barrier lockstep. Slowest = L0 waves 0-3 (2 tiles = 4 MFMA + 2 GMATH
// ~40 VALU) which ALSO carried the x-staging duty (tid<256: cvt + ds_write
// + guarded global load, +15% issue). Move x duty to lanes 512-767 = L1
// waves 8-11 (lightest: 1 tile, ~25 VALU -> ~31). Same addresses, same
// parity protocol; x write from an L1 wave is equally visible across the
// barrier. Refuted so far: barrier-count (r20), vmcnt-drain (r22),
// read-duplication (r25), bank-uniformity (r26).
#define BAR() asm volatile("s_waitcnt lgkmcnt(0)\n\ts_barrier" ::: "memory")

// A-frag over unified K-concat rows [h_self(40) | input(KX)] (r15-proven mapping).
__device__ bf16x8 afrag(const float* Whh, const float* Wih, int KX,
                        int rh, int rx, int c, int qrow) {
    bf16x8 f;
    #pragma unroll
    for (int j = 0; j < 8; ++j) f[j] = 0;
    #pragma unroll
    for (int j = 0; j < 8; ++j) {
        const int k = 32 * c + qrow * 8 + j;
        if (k < 40) {
            if (rh >= 0) f[j] = (short)bf16_rne(Whh[rh * 40 + k]);
        } else if (k < 40 + KX) {
            if (rx >= 0) f[j] = (short)bf16_rne(Wih[rx * KX + (k - 40)]);
        }
    }
    return f;
}

__global__ __launch_bounds__(NTHR, 4)
void gru2_kernel(const float* __restrict__ x,
                 const float* __restrict__ Wih0, const float* __restrict__ Whh0,
                 const float* __restrict__ bih0, const float* __restrict__ bhh0,
                 const float* __restrict__ Wih1, const float* __restrict__ Whh1,
                 const float* __restrict__ bih1, const float* __restrict__ bhh1,
                 float* __restrict__ out)
{
    __shared__ __align__(16) unsigned short S[STOT];

    const int tid  = threadIdx.x;
    const int wid  = tid >> 6;     // 0..15
    const int l    = tid & 63;
    const int col  = l & 15;       // example / MFMA col
    const int qrow = l >> 4;
    const int ps   = (l & 15) & 3; // slot (0=r,1=z,2=nx,3=nh)
    const int pu   = (l & 15) >> 2;
    const int e0   = blockIdx.x * EPB;

    const bool isL1 = wid >= 6;
    const int  NT   = (!isL1 && wid < 4) ? 2 : 1;
    const int  TA   = isL1 ? (wid - 6) : (wid < 4 ? 2 * wid : wid + 4);
    const int  TB   = (NT == 2) ? TA + 1 : TA;
    const bool dB   = (NT != 2);

    const float* Whh = isL1 ? Whh1 : Whh0;
    const float* Wih = isL1 ? Wih1 : Wih0;
    const float* bih = isL1 ? bih1 : bih0;
    const float* bhh = isL1 ? bhh1 : bhh0;
    const int KX = isL1 ? 40 : 16;

    // ---- A-frags + biases ----
    bf16x8 ZF;
    #pragma unroll
    for (int j = 0; j < 8; ++j) ZF[j] = 0;
    bf16x8 F00=ZF,F01=ZF,F02=ZF, F10=ZF,F11=ZF;
    f32x4 BB0, BB1;
    {
#define RRX(u, RH, RX) \
        const int RH = (ps == 2) ? -1 : (ps == 0 ? (u) : ps == 1 ? 40 + (u) : 80 + (u)); \
        const int RX = (ps == 3) ? -1 : (ps == 0 ? (u) : ps == 1 ? 40 + (u) : 80 + (u));
        {
            const int u0 = 4 * TA + pu;
            RRX(u0, rh0, rx0);
            F00 = afrag(Whh, Wih, KX, rh0, rx0, 0, qrow);
            F01 = afrag(Whh, Wih, KX, rh0, rx0, 1, qrow);
            if (isL1) F02 = afrag(Whh, Wih, KX, rh0, rx0, 2, qrow);
        }
        if (NT == 2) {
            const int u1 = 4 * TB + pu;
            RRX(u1, rh1, rx1);
            F10 = afrag(Whh, Wih, KX, rh1, rx1, 0, qrow);
            F11 = afrag(Whh, Wih, KX, rh1, rx1, 1, qrow);
        }
        const int uc0 = 4 * TA + qrow;
        const int uc1 = 4 * TB + qrow;
        BB0[0] = bih[uc0] + bhh[uc0];
        BB0[1] = bih[40 + uc0] + bhh[40 + uc0];
        BB0[2] = bih[80 + uc0];
        BB0[3] = bhh[80 + uc0];
        BB1[0] = dB ? 0.f : (bih[uc1] + bhh[uc1]);
        BB1[1] = dB ? 0.f : (bih[40 + uc1] + bhh[40 + uc1]);
        BB1[2] = dB ? 0.f : bih[80 + uc1];
        BB1[3] = dB ? 0.f : bhh[80 + uc1];
    }
    PINV(F00); PINV(F01); PINV(F02);
    PINV(F10); PINV(F11);
    PINV(BB0); PINV(BB1);

    // ---- per-lane LDS addresses (shorts; parity selected at compile time) ----
    // L0 row [h0(40)|x(16)|pad(16)]: chunk0 at 8q..; chunk1 at 32+8q..:
    // qrow0 h0[32..39], qrow1 x[0..7], qrow2 x[8..15], qrow3 pad=0.
    const int rd0 = col * RR0 + 8 * qrow;
    const int rd1 = rd0 + 32;
    // L1 concat [h1(40) | h0(40)]: group g = 4c + qrow; precompute parities.
    int g0p0, g0p1, g1p0, g1p1, g2p0, g2p1;
    {
        auto ga = [&](int g, int p) -> int {
            if (g < 5)  return OL1 + p * P1 + col * RR1 + 8 * g;      // h1
            if (g < 10) return p * P0 + col * RR0 + 8 * (g - 5);      // h0
            return p * P0 + col * RR0;                                // dead (A=0)
        };
        g0p0 = ga(qrow, 0);     g0p1 = ga(qrow, 1);
        g1p0 = ga(4 + qrow, 0); g1p1 = ga(4 + qrow, 1);
        g2p0 = ga(8 + qrow, 0); g2p1 = ga(8 + qrow, 1);
    }
    // write offsets (parity (1-RP) applied as compile-time immediate)
    const int w0  = col * RR0 + 4 * TA + qrow;         // L0 tile A unit
    const int w0b = col * RR0 + 4 * TB + qrow;         // L0 tile B unit
    const int w1  = OL1 + col * RR1 + 4 * TA + qrow;   // L1 unit
    unsigned short* Sb = &S[0];
    float hA0 = 0.f, hA1 = 0.f;

    // ---- x staging lanes: tid 512..767 (= L1 waves 8-11, lightest load) ----
    const bool xth = (tid >= 512) && (tid < 768);
    const int xe = (tid >> 4) & 15, xk = tid & 15;
    const int xsl = xe * RR0 + 40 + xk;                // + parity at use
    const float* xrow = x + (size_t)(e0 + xe) * (T_STEPS * 16) + xk;

    // ---- zero LDS (initial h = 0; pads must stay 0) ----
    for (int idx = tid; idx < STOT; idx += NTHR) Sb[idx] = 0;
    __syncthreads();
    // x[0] into parity 0; ring holds x[1..4]
    float XA = 0.f, XB = 0.f, XC = 0.f, XD = 0.f;
    if (xth) {
        Sb[xsl] = bf16_cvt(xrow[0]);
        XA = xrow[16];       // x[1]
        XB = xrow[32];       // x[2]
        XC = xrow[48];       // x[3]
        XD = xrow[64];       // x[4]
    }
    __syncthreads();

#define GMATH(C, H) \
    const float r_ = sigm(C[0]); \
    const float z_ = sigm(C[1]); \
    const float n_ = tanh_f(C[2] + r_ * C[3]); \
    H = n_ + z_ * (H - n_);

    // BODY(RP, XQ): step t. xth lanes (in L1 waves) stage x[t+1] to parity
    // (1-RP) for L0's step-t+1 read, then refill XQ with x[t+5].
#define BODY(RP, XQ) { \
    if (!isL1) { \
        if (t < T_STEPS) { \
            const bf16x8 S0 = *(const bf16x8*)(Sb + rd0 + (RP) * P0); \
            const bf16x8 S1 = *(const bf16x8*)(Sb + rd1 + (RP) * P0); \
            f32x4 c0 = __builtin_amdgcn_mfma_f32_16x16x32_bf16(F00, S0, BB0, 0, 0, 0); \
            MF(F01, S1, c0); \
            { GMATH(c0, hA0); Sb[w0 + (1 - (RP)) * P0] = bf16_cvt(hA0); } \
            if (NT == 2) { \
                f32x4 c1 = __builtin_amdgcn_mfma_f32_16x16x32_bf16(F10, S0, BB1, 0, 0, 0); \
                MF(F11, S1, c1); \
                GMATH(c1, hA1); Sb[w0b + (1 - (RP)) * P0] = bf16_cvt(hA1); \
            } \
        } \
    } else { \
        const bf16x8 S0 = *(const bf16x8*)(Sb + ((RP) ? g0p1 : g0p0)); \
        const bf16x8 S1 = *(const bf16x8*)(Sb + ((RP) ? g1p1 : g1p0)); \
        const bf16x8 S2 = *(const bf16x8*)(Sb + ((RP) ? g2p1 : g2p0)); \
        if (xth && t < T_STEPS - 1) { \
            Sb[xsl + (1 - (RP)) * P0] = bf16_cvt(XQ); \
            if (t + 5 < T_STEPS) XQ = xrow[(t + 5) * 16]; \
        } \
        f32x4 c = __builtin_amdgcn_mfma_f32_16x16x32_bf16(F00, S0, BB0, 0, 0, 0); \
        MF(F01, S1, c); MF(F02, S2, c); \
        if (t > 0) { GMATH(c, hA0); Sb[w1 + (1 - (RP)) * P1] = bf16_cvt(hA0); } \
    } \
    ++t; \
    BAR(); }

    int t = 0;
    #pragma unroll 1
    for (int it = 0; it < 64; ++it) {
        BODY(0, XA)
        BODY(1, XB)
        BODY(0, XC)
        BODY(1, XD)
    }
    BODY(0, XA)   // t = 256: L1 finishes h1[255]; L0 inactive

    // ---- h1[255] straight from registers (10 L1 waves x 4 units = 40) ----
    if (isL1) {
        out[(size_t)(e0 + col) * HID + 4 * TA + qrow] = hA0;
    }
}

extern "C" void kernel_launch(void* const* d_in, const int* in_sizes, int n_in,
                              void* d_out, int out_size, void* d_ws, size_t ws_size,
                              hipStream_t stream) {
    const float* x    = (const float*)d_in[0];
    const float* Wih0 = (const float*)d_in[1];
    const float* Whh0 = (const float*)d_in[2];
    const float* bih0 = (const float*)d_in[3];
    const float* bhh0 = (const float*)d_in[4];
    const float* Wih1 = (const float*)d_in[5];
    const float* Whh1 = (const float*)d_in[6];
    const float* bih1 = (const float*)d_in[7];
    const float* bhh1 = (const float*)d_in[8];
    float* out = (float*)d_out;

    dim3 grid(4096 / EPB), block(NTHR);
    hipLaunchKernelGGL(gru2_kernel, grid, block, 0, stream,
                       x, Wih0, Whh0, bih0, bhh0, Wih1, Whh1, bih1, bhh1, out);
}